// Round 7
// baseline (329.931 us; speedup 1.0000x reference)
//
#include <hip/hip_runtime.h>

// LoRAConnector: B=4, T=2048, N=4, C=1024, A=8, nC=4096, SINKHORN_ITERS=20
//
// Round 8: counted-vmcnt pipeline (T3/T4) — kill the __syncthreads drain.
//  R6 post-mortem: no spill, 6 blocks/CU, but ~1290 cy/iter vs ~250 cy of
//  work. Cause: __syncthreads emits s_waitcnt vmcnt(0) before s_barrier,
//  draining the HBM-cold x prefetch (~900 cy) EVERY iteration; prefetch
//  distance can't help because the barrier drains everything regardless.
//  Fix (guide T4, m218: counted vs drain-0 = +38-73%):
//   - raw s_barrier + asm "s_waitcnt vmcnt(5)" at iter top. Issue order
//     pinned by sched_barrier(0): STAGE(m+1) [3 gl_lds] then x/w(m+2) [5].
//     Outstanding at iter-m top = X(m)5 + S(m)3 + X(m+1)5 = 13; vmcnt(5)
//     retires oldest 8 = {X(m), S(m)}: tile m resident AND x(m) ready,
//     with x having had 2 iterations (~600cy) of flight. Last iter vmcnt(0).
//   - x/w prefetch depth 2: xnA/xnB + wnA/wnB, pair-unrolled loop so buffer
//     names and bf are compile-time (rule #20). +5 VGPR vs R6.
//   - race logic unchanged: staging into buf bf^1 starts only after the
//     barrier that ends all reads of bf^1's previous tile (single barrier
//     per tile, same as the __syncthreads version).
//  Geometry unchanged from R6 (verified): TD=128, NT=32, 12KB/tile dbuf,
//  25.5KB LDS -> 6 blocks/CU; half-split outputs, acc[12][4]+ss, no spill.
//  Gates: WRITE_SIZE == 131072 KB exactly; VGPR 64-76; absmax 0.03125.

#define BT 8192        // B*T tokens
#define NC 4096        // N*C
#define NC4 1024       // NC/4
#define NT 32          // tiles
#define TD 128         // d's per tile

__global__ __launch_bounds__(256) void lora_connector_kernel(
    const float* __restrict__ x,
    const float* __restrict__ inw,
    const float* __restrict__ phi_pre,
    const float* __restrict__ phi_post,
    const float* __restrict__ phi_res,
    const float* __restrict__ b_pre,
    const float* __restrict__ b_post,
    const float* __restrict__ b_res,
    const float* __restrict__ alpha_pre,
    const float* __restrict__ alpha_post,
    const float* __restrict__ alpha_res,
    const int*   __restrict__ adapter_indices,
    float* __restrict__ out)
{
    const int tid = threadIdx.x;
    const int g   = tid & 3;        // token for phase 2c/3
    const int l   = tid >> 2;       // c4-slice for phase 3
    const int wvid= tid >> 6;       // wave 0..3
    const int ln  = tid & 63;       // lane within wave
    const int dl  = tid & 127;      // d-slice within tile
    const int half= tid >> 7;       // output half (wave-uniform)
    const int blk = blockIdx.x;
    const int b   = blk >> 9;       // block-uniform batch
    const int idx = adapter_indices[b];

    const float4* __restrict__ pp4 = (const float4*)(phi_pre  + (size_t)idx * (NC * 4));
    const float4* __restrict__ po4 = (const float4*)(phi_post + (size_t)idx * (NC * 4));
    const float4* __restrict__ pr4 = (const float4*)(phi_res  + (size_t)idx * (NC * 16));
    const float*  __restrict__ inwp = inw + (size_t)idx * NC + dl;      // + m*TD
    const float*  __restrict__ xb   = x + (size_t)(blk * 4) * NC + dl;  // + j*NC + m*TD

    // double-buffered phi tile, 768 float4 = 12KB per buffer:
    //  [0..127]=pp[d], [128..255]=po[d], [256+q*128+d]=prT[q][d]
    __shared__ float4 tileL[2][768];
    __shared__ float red[4][4][14];

    // staging: 12 chunks of 1KB per tile; wave wvid owns chunks 3*wvid..+2.
    // dest = tileL[bf][c*64+ln] (linear, global_load_lds requirement);
    // phi_res transposed via per-lane SOURCE address (m173): k=c-4, q=k>>1,
    // subd=(k&1)*64+ln, src=pr4[subd*4+q] -> lands at prT[q][subd].
    const float4* sg[3];
    int sstr[3];
    #pragma unroll
    for (int i = 0; i < 3; ++i) {
        const int c = wvid * 3 + i;              // wave-uniform
        const float4* bp; int off, str;
        if (c < 4) {
            bp  = (c < 2) ? pp4 : po4;
            off = ((c & 1) << 6) + ln;
            str = TD;                            // 128 float4 per tile
        } else {
            const int k = c - 4;
            bp  = pr4;
            off = ((((k & 1) << 6) + ln) << 2) + (k >> 1);
            str = TD * 4;                        // 512 float4 per tile
        }
        sg[i] = bp + off;
        sstr[i] = str;
    }

    #define STAGE_TILE(MT, BF)                                                   \
    {                                                                            \
        _Pragma("unroll")                                                        \
        for (int i = 0; i < 3; ++i) {                                            \
            __builtin_amdgcn_global_load_lds(                                    \
                (const __attribute__((address_space(1))) void*)(sg[i] + (size_t)(MT) * sstr[i]), \
                (__attribute__((address_space(3))) void*)&tileL[BF][((wvid * 3 + i) << 6) + ln], \
                16, 0, 0);                                                       \
        }                                                                        \
    }

    #define XW_PRE(MT, XR, WR)                                                   \
    {                                                                            \
        _Pragma("unroll")                                                        \
        for (int j = 0; j < 4; ++j) XR[j] = xb[j * NC + (MT) * TD];              \
        WR = inwp[(MT) * TD];                                                    \
    }

    float acc[12][4];
    float ss[4];
    #pragma unroll
    for (int j = 0; j < 12; ++j) {
        acc[j][0] = 0.0f; acc[j][1] = 0.0f; acc[j][2] = 0.0f; acc[j][3] = 0.0f;
    }
    ss[0] = ss[1] = ss[2] = ss[3] = 0.0f;

    const int ba = half * 384 + dl;  // this thread's 3 reads: ba, ba+128, ba+256

    // ---- Prologue: S(0), then X(0)->A, X(1)->B (issue order matters) ----
    float xnA[4], xnB[4], wnA, wnB;
    STAGE_TILE(0, 0);
    __builtin_amdgcn_sched_barrier(0);
    XW_PRE(0, xnA, wnA);
    XW_PRE(1, xnB, wnB);

    // One iteration. BF is a literal; XC/WC are the buffer consumed (tile M)
    // and refilled for tile M+2. WAITN: 5 in steady state (retires oldest 8 =
    // X(M)+S(M), leaves X(M+1) in flight), 0 only for the final iteration.
    #define ITER(M, BF, XC, WC, WAITN)                                           \
    {                                                                            \
        __builtin_amdgcn_sched_barrier(0);                                       \
        asm volatile("s_waitcnt vmcnt(" #WAITN ")" ::: "memory");                \
        __builtin_amdgcn_sched_barrier(0);                                       \
        __builtin_amdgcn_s_barrier();                                            \
        __builtin_amdgcn_sched_barrier(0);                                       \
        if ((M) < NT - 1) STAGE_TILE((M) + 1, (BF) ^ 1);                         \
        __builtin_amdgcn_sched_barrier(0);                                       \
        float s[4];                                                              \
        _Pragma("unroll")                                                        \
        for (int j = 0; j < 4; ++j) {                                            \
            const float xv = XC[j];                                              \
            s[j] = xv * WC;                                                      \
            ss[j] = fmaf(xv, xv, ss[j]);                                         \
        }                                                                        \
        if ((M) < NT - 2) XW_PRE((M) + 2, XC, WC);                               \
        const float4 a = tileL[BF][ba];                                          \
        const float4 p = tileL[BF][ba + 128];                                    \
        const float4 r = tileL[BF][ba + 256];                                    \
        _Pragma("unroll")                                                        \
        for (int j = 0; j < 4; ++j) {                                            \
            acc[0][j]  = fmaf(s[j], a.x, acc[0][j]);                             \
            acc[1][j]  = fmaf(s[j], a.y, acc[1][j]);                             \
            acc[2][j]  = fmaf(s[j], a.z, acc[2][j]);                             \
            acc[3][j]  = fmaf(s[j], a.w, acc[3][j]);                             \
            acc[4][j]  = fmaf(s[j], p.x, acc[4][j]);                             \
            acc[5][j]  = fmaf(s[j], p.y, acc[5][j]);                             \
            acc[6][j]  = fmaf(s[j], p.z, acc[6][j]);                             \
            acc[7][j]  = fmaf(s[j], p.w, acc[7][j]);                             \
            acc[8][j]  = fmaf(s[j], r.x, acc[8][j]);                             \
            acc[9][j]  = fmaf(s[j], r.y, acc[9][j]);                             \
            acc[10][j] = fmaf(s[j], r.z, acc[10][j]);                            \
            acc[11][j] = fmaf(s[j], r.w, acc[11][j]);                            \
        }                                                                        \
    }

    // ---- Phase 1: 32 tiles, pair-unrolled so BF and buffers are literal ----
    #pragma unroll 1
    for (int m = 0; m < NT - 2; m += 2) {
        ITER(m,     0, xnA, wnA, 5);
        ITER(m + 1, 1, xnB, wnB, 5);
    }
    ITER(NT - 2, 0, xnA, wnA, 5);
    ITER(NT - 1, 1, xnB, wnB, 0);
    #undef ITER

    // ---- Phase 2a: token-redistributing butterfly (wave sum) ----
    // bits 0,1 combine while assigning token = ln&3 (static reg indices,
    // rule #20); bits 2..5 finish. Lane ends holding token (ln&3)'s sums.
    float t12[13];
    #define RED4(V0, V1, V2, V3, DST)                                   \
    {                                                                   \
        const float u0 = (V0) + __shfl_xor((V0), 1);                    \
        const float u1 = (V1) + __shfl_xor((V1), 1);                    \
        const float u2 = (V2) + __shfl_xor((V2), 1);                    \
        const float u3 = (V3) + __shfl_xor((V3), 1);                    \
        const float r0 = (ln & 1) ? u1 : u0;                            \
        const float r1 = (ln & 1) ? u3 : u2;                            \
        const float w0 = r0 + __shfl_xor(r0, 2);                        \
        const float w1 = r1 + __shfl_xor(r1, 2);                        \
        float tv = (ln & 2) ? w1 : w0;                                  \
        tv += __shfl_xor(tv, 4);  tv += __shfl_xor(tv, 8);              \
        tv += __shfl_xor(tv, 16); tv += __shfl_xor(tv, 32);             \
        (DST) = tv;                                                     \
    }
    #pragma unroll
    for (int j = 0; j < 12; ++j)
        RED4(acc[j][0], acc[j][1], acc[j][2], acc[j][3], t12[j]);
    RED4(ss[0], ss[1], ss[2], ss[3], t12[12]);
    #undef RED4

    // ---- Phase 2b: cross-wave/-half assembly via LDS ----
    // waves 0,1 (half0): outputs are tot[0..11] + ss; waves 2,3: tot[12..23].
    if (ln < 4) {
        #pragma unroll
        for (int j = 0; j < 13; ++j) red[wvid][ln][j] = t12[j];
    }
    __syncthreads();
    float tot[25];
    #pragma unroll
    for (int j = 0; j < 12; ++j) {
        tot[j]      = red[0][g][j] + red[1][g][j];
        tot[12 + j] = red[2][g][j] + red[3][g][j];
    }
    tot[24] = red[0][g][12] + red[1][g][12];

    // ---- Phase 2c: rms, gates, sinkhorn (token g per thread) ----
    const float inv_rms = rsqrtf(tot[24] * (1.0f / 4096.0f) + 1e-5f);
    const float apre  = alpha_pre[idx];
    const float apost = alpha_post[idx];
    const float ares  = alpha_res[idx];

    float Hpre[4], Hpost[4];
    #pragma unroll
    for (int n = 0; n < 4; ++n) {
        const float zp = fmaf(apre,  tot[n]     * inv_rms, b_pre[idx * 4 + n]);
        Hpre[n]  = 1.0f / (1.0f + __expf(-zp));
        const float zq = fmaf(apost, tot[4 + n] * inv_rms, b_post[idx * 4 + n]);
        Hpost[n] = 2.0f / (1.0f + __expf(-zq));
    }

    // lane owns element (si,sj) of token g's 4x4 matrix
    const int s16 = ln >> 2;         // 0..15
    const int sj = s16 & 3;
    const int si = s16 >> 2;
    float Mv = __expf(fmaf(ares, tot[8 + si * 4 + sj] * inv_rms,
                           b_res[idx * 16 + si * 4 + sj]));
    #pragma unroll
    for (int it = 0; it < 20; ++it) {
        float rs = Mv + __shfl_xor(Mv, 4);   // sum over j (lane bits 2,3)
        rs += __shfl_xor(rs, 8);
        Mv *= __builtin_amdgcn_rcpf(rs);
        float cs = Mv + __shfl_xor(Mv, 16);  // sum over i (lane bits 4,5)
        cs += __shfl_xor(cs, 32);
        Mv *= __builtin_amdgcn_rcpf(cs);
    }

    // gather full W[i][j] = M[i][j] + Hpost[i]*Hpre[j] for this thread's token
    float W[4][4];
    #pragma unroll
    for (int sq = 0; sq < 16; ++sq) {
        const float mm = __shfl(Mv, sq * 4 + g);
        W[sq >> 2][sq & 3] = fmaf(Hpost[sq >> 2], Hpre[sq & 3], mm);
    }

    // ---- Phase 3: out[tok][i*256+c4] = sum_j W[i][j] * x[tok][j*256+c4] ----
    const int tok = blk * 4 + g;
    const float4* __restrict__ x4p = (const float4*)x + (size_t)tok * NC4;
    float4* __restrict__ out4 = (float4*)out + (size_t)tok * NC4;
    #pragma unroll
    for (int k = 0; k < 4; ++k) {
        const int c4 = k * 64 + l;
        const float4 x0 = x4p[0 * 256 + c4];
        const float4 x1 = x4p[1 * 256 + c4];
        const float4 x2 = x4p[2 * 256 + c4];
        const float4 x3 = x4p[3 * 256 + c4];
        #pragma unroll
        for (int i = 0; i < 4; ++i) {
            float4 o;
            o.x = fmaf(W[i][0], x0.x, fmaf(W[i][1], x1.x, fmaf(W[i][2], x2.x, W[i][3] * x3.x)));
            o.y = fmaf(W[i][0], x0.y, fmaf(W[i][1], x1.y, fmaf(W[i][2], x2.y, W[i][3] * x3.y)));
            o.z = fmaf(W[i][0], x0.z, fmaf(W[i][1], x1.z, fmaf(W[i][2], x2.z, W[i][3] * x3.z)));
            o.w = fmaf(W[i][0], x0.w, fmaf(W[i][1], x1.w, fmaf(W[i][2], x2.w, W[i][3] * x3.w)));
            out4[i * 256 + c4] = o;
        }
    }
    #undef STAGE_TILE
    #undef XW_PRE
}

extern "C" void kernel_launch(void* const* d_in, const int* in_sizes, int n_in,
                              void* d_out, int out_size, void* d_ws, size_t ws_size,
                              hipStream_t stream) {
    const float* x         = (const float*)d_in[0];
    const float* inw       = (const float*)d_in[1];
    const float* phi_pre   = (const float*)d_in[2];
    const float* phi_post  = (const float*)d_in[3];
    const float* phi_res   = (const float*)d_in[4];
    const float* b_pre     = (const float*)d_in[5];
    const float* b_post    = (const float*)d_in[6];
    const float* b_res     = (const float*)d_in[7];
    const float* alpha_pre = (const float*)d_in[8];
    const float* alpha_post= (const float*)d_in[9];
    const float* alpha_res = (const float*)d_in[10];
    const int*   adapter   = (const int*)d_in[11];
    float* out = (float*)d_out;

    dim3 grid(BT / 4);   // 2048 blocks, 4 tokens each
    dim3 block(256);
    lora_connector_kernel<<<grid, block, 0, stream>>>(
        x, inw, phi_pre, phi_post, phi_res,
        b_pre, b_post, b_res,
        alpha_pre, alpha_post, alpha_res,
        adapter, out);
}

// Round 8
// 318.521 us; speedup vs baseline: 1.0358x; 1.0358x over previous
//
#include <hip/hip_runtime.h>

// LoRAConnector: B=4, T=2048, N=4, C=1024, A=8, nC=4096, SINKHORN_ITERS=20
//
// Round 9: two-kernel split (ablation + streaming-phase liberation).
//  R7 post-mortem: counted-vmcnt + sched_barrier walls regressed 137.5->156
//  (m141 failure mode: over-pinning; VALUBusy fell 27->19.5). Reverted.
//  Three rounds of stall-models have failed to explain R6's 137us (VALU
//  ~21-37us, HBM ~40us, LDS ~0 -> ~90us unattributed). Per the ablate-first
//  rule, split the op at its natural seam and let rocprof attribute:
//   Kernel A (lora_w_kernel): R6 structure verbatim minus phase 3; computes
//     per-token W[4][4] = M + Hpost x Hpre and writes it to d_ws (512 KB).
//   Kernel B (lora_mix_kernel): pure streaming out[i,c]=sum_j W[i,j]x[j,c].
//     8192 blocks x 256 threads, one token/block, no LDS/barriers, W rows
//     read as broadcast float4; x likely L3-resident after A (FETCH of B
//     measures this directly).
//  W transits memory as exact fp32 -> results bitwise identical to R6
//  (absmax 0.03125). Stream-ordered launches, no sync/alloc (graph-safe).
//  Decision rule: if A ~130us -> the stall is phase-1-internal, attack its
//  pipeline next; if A+B ~60+50 -> keep split and tune B's BW / A's tail.

#define BT 8192        // B*T tokens
#define NC 4096        // N*C
#define NC4 1024       // NC/4
#define NT 32          // tiles
#define TD 128         // d's per tile

// ---------------- Kernel A: reduction pass -> W[tok][4][4] ----------------
__global__ __launch_bounds__(256) void lora_w_kernel(
    const float* __restrict__ x,
    const float* __restrict__ inw,
    const float* __restrict__ phi_pre,
    const float* __restrict__ phi_post,
    const float* __restrict__ phi_res,
    const float* __restrict__ b_pre,
    const float* __restrict__ b_post,
    const float* __restrict__ b_res,
    const float* __restrict__ alpha_pre,
    const float* __restrict__ alpha_post,
    const float* __restrict__ alpha_res,
    const int*   __restrict__ adapter_indices,
    float* __restrict__ wsf)
{
    const int tid = threadIdx.x;
    const int g   = tid & 3;        // token for phase 2c
    const int wvid= tid >> 6;       // wave 0..3
    const int ln  = tid & 63;       // lane within wave
    const int dl  = tid & 127;      // d-slice within tile
    const int half= tid >> 7;       // output half (wave-uniform)
    const int blk = blockIdx.x;
    const int b   = blk >> 9;       // block-uniform batch
    const int idx = adapter_indices[b];

    const float4* __restrict__ pp4 = (const float4*)(phi_pre  + (size_t)idx * (NC * 4));
    const float4* __restrict__ po4 = (const float4*)(phi_post + (size_t)idx * (NC * 4));
    const float4* __restrict__ pr4 = (const float4*)(phi_res  + (size_t)idx * (NC * 16));
    const float*  __restrict__ inwp = inw + (size_t)idx * NC + dl;      // + m*TD
    const float*  __restrict__ xb   = x + (size_t)(blk * 4) * NC + dl;  // + j*NC + m*TD

    // double-buffered phi tile, 768 float4 = 12KB per buffer:
    //  [0..127]=pp[d], [128..255]=po[d], [256+q*128+d]=prT[q][d]
    __shared__ float4 tileL[2][768];
    __shared__ float red[4][4][14];

    // staging: 12 chunks of 1KB per tile; wave wvid owns chunks 3*wvid..+2.
    // dest = tileL[bf][c*64+ln] (linear, global_load_lds requirement);
    // phi_res transposed via per-lane SOURCE address (m173): k=c-4, q=k>>1,
    // subd=(k&1)*64+ln, src=pr4[subd*4+q] -> lands at prT[q][subd].
    const float4* sg[3];
    int sstr[3];
    #pragma unroll
    for (int i = 0; i < 3; ++i) {
        const int c = wvid * 3 + i;              // wave-uniform
        const float4* bp; int off, str;
        if (c < 4) {
            bp  = (c < 2) ? pp4 : po4;
            off = ((c & 1) << 6) + ln;
            str = TD;                            // 128 float4 per tile
        } else {
            const int k = c - 4;
            bp  = pr4;
            off = ((((k & 1) << 6) + ln) << 2) + (k >> 1);
            str = TD * 4;                        // 512 float4 per tile
        }
        sg[i] = bp + off;
        sstr[i] = str;
    }

    #define STAGE_TILE(MT, BF)                                                   \
    {                                                                            \
        _Pragma("unroll")                                                        \
        for (int i = 0; i < 3; ++i) {                                            \
            __builtin_amdgcn_global_load_lds(                                    \
                (const __attribute__((address_space(1))) void*)(sg[i] + (size_t)(MT) * sstr[i]), \
                (__attribute__((address_space(3))) void*)&tileL[BF][((wvid * 3 + i) << 6) + ln], \
                16, 0, 0);                                                       \
        }                                                                        \
    }

    // ---- Prologue: stage tile 0; prefetch x,w for tile 0 ----
    STAGE_TILE(0, 0);

    float acc[12][4];
    float ss[4];
    #pragma unroll
    for (int j = 0; j < 12; ++j) {
        acc[j][0] = 0.0f; acc[j][1] = 0.0f; acc[j][2] = 0.0f; acc[j][3] = 0.0f;
    }
    ss[0] = ss[1] = ss[2] = ss[3] = 0.0f;

    float xn[4], wn;
    #pragma unroll
    for (int j = 0; j < 4; ++j) xn[j] = xb[j * NC];
    wn = inwp[0];

    const int ba = half * 384 + dl;  // this thread's 3 reads: ba, ba+128, ba+256

    // ---- Phase 1: 32 tiles; barrier -> stage next -> consume current ----
    #pragma unroll 1
    for (int m = 0; m < NT; ++m) {
        const int bf = m & 1;
        __syncthreads();                         // tile m resident (vmcnt drain)
        if (m < NT - 1) STAGE_TILE(m + 1, bf ^ 1);   // phi m+1 in flight

        const float wv = wn;
        float s[4];
        #pragma unroll
        for (int j = 0; j < 4; ++j) {
            const float xv = xn[j];
            s[j] = xv * wv;
            ss[j] = fmaf(xv, xv, ss[j]);         // duplicated across halves; only half0's used
        }
        if (m < NT - 1) {                        // x,w m+1 in flight
            #pragma unroll
            for (int j = 0; j < 4; ++j) xn[j] = xb[j * NC + (m + 1) * TD];
            wn = inwp[(m + 1) * TD];
        }

        const float4 a = tileL[bf][ba];          // half0: pp[d]   half1: prT[1][d]
        const float4 p = tileL[bf][ba + 128];    // half0: po[d]   half1: prT[2][d]
        const float4 r = tileL[bf][ba + 256];    // half0: prT[0]  half1: prT[3][d]
        #pragma unroll
        for (int j = 0; j < 4; ++j) {
            acc[0][j]  = fmaf(s[j], a.x, acc[0][j]);
            acc[1][j]  = fmaf(s[j], a.y, acc[1][j]);
            acc[2][j]  = fmaf(s[j], a.z, acc[2][j]);
            acc[3][j]  = fmaf(s[j], a.w, acc[3][j]);
            acc[4][j]  = fmaf(s[j], p.x, acc[4][j]);
            acc[5][j]  = fmaf(s[j], p.y, acc[5][j]);
            acc[6][j]  = fmaf(s[j], p.z, acc[6][j]);
            acc[7][j]  = fmaf(s[j], p.w, acc[7][j]);
            acc[8][j]  = fmaf(s[j], r.x, acc[8][j]);
            acc[9][j]  = fmaf(s[j], r.y, acc[9][j]);
            acc[10][j] = fmaf(s[j], r.z, acc[10][j]);
            acc[11][j] = fmaf(s[j], r.w, acc[11][j]);
        }
    }

    // ---- Phase 2a: token-redistributing butterfly (wave sum) ----
    float t12[13];
    #define RED4(V0, V1, V2, V3, DST)                                   \
    {                                                                   \
        const float u0 = (V0) + __shfl_xor((V0), 1);                    \
        const float u1 = (V1) + __shfl_xor((V1), 1);                    \
        const float u2 = (V2) + __shfl_xor((V2), 1);                    \
        const float u3 = (V3) + __shfl_xor((V3), 1);                    \
        const float r0 = (ln & 1) ? u1 : u0;                            \
        const float r1 = (ln & 1) ? u3 : u2;                            \
        const float w0 = r0 + __shfl_xor(r0, 2);                        \
        const float w1 = r1 + __shfl_xor(r1, 2);                        \
        float tv = (ln & 2) ? w1 : w0;                                  \
        tv += __shfl_xor(tv, 4);  tv += __shfl_xor(tv, 8);              \
        tv += __shfl_xor(tv, 16); tv += __shfl_xor(tv, 32);             \
        (DST) = tv;                                                     \
    }
    #pragma unroll
    for (int j = 0; j < 12; ++j)
        RED4(acc[j][0], acc[j][1], acc[j][2], acc[j][3], t12[j]);
    RED4(ss[0], ss[1], ss[2], ss[3], t12[12]);
    #undef RED4

    // ---- Phase 2b: cross-wave/-half assembly via LDS ----
    if (ln < 4) {
        #pragma unroll
        for (int j = 0; j < 13; ++j) red[wvid][ln][j] = t12[j];
    }
    __syncthreads();
    float tot[25];
    #pragma unroll
    for (int j = 0; j < 12; ++j) {
        tot[j]      = red[0][g][j] + red[1][g][j];
        tot[12 + j] = red[2][g][j] + red[3][g][j];
    }
    tot[24] = red[0][g][12] + red[1][g][12];

    // ---- Phase 2c: rms, gates, sinkhorn (token g per thread) ----
    const float inv_rms = rsqrtf(tot[24] * (1.0f / 4096.0f) + 1e-5f);
    const float apre  = alpha_pre[idx];
    const float apost = alpha_post[idx];
    const float ares  = alpha_res[idx];

    float Hpre[4], Hpost[4];
    #pragma unroll
    for (int n = 0; n < 4; ++n) {
        const float zp = fmaf(apre,  tot[n]     * inv_rms, b_pre[idx * 4 + n]);
        Hpre[n]  = 1.0f / (1.0f + __expf(-zp));
        const float zq = fmaf(apost, tot[4 + n] * inv_rms, b_post[idx * 4 + n]);
        Hpost[n] = 2.0f / (1.0f + __expf(-zq));
    }

    // lane owns element (si,sj) of token g's 4x4 matrix
    const int s16 = ln >> 2;         // 0..15
    const int sj = s16 & 3;
    const int si = s16 >> 2;
    float Mv = __expf(fmaf(ares, tot[8 + si * 4 + sj] * inv_rms,
                           b_res[idx * 16 + si * 4 + sj]));
    #pragma unroll
    for (int it = 0; it < 20; ++it) {
        float rs = Mv + __shfl_xor(Mv, 4);   // sum over j (lane bits 2,3)
        rs += __shfl_xor(rs, 8);
        Mv *= __builtin_amdgcn_rcpf(rs);
        float cs = Mv + __shfl_xor(Mv, 16);  // sum over i (lane bits 4,5)
        cs += __shfl_xor(cs, 32);
        Mv *= __builtin_amdgcn_rcpf(cs);
    }

    // ---- write W[tok][si][sj] = M + Hpost[si]*Hpre[sj] (wave 0 only) ----
    // select-chains keep Hpre/Hpost register indices static (rule #20).
    if (wvid == 0) {
        const float hpo = (si == 0) ? Hpost[0] : (si == 1) ? Hpost[1]
                        : (si == 2) ? Hpost[2] : Hpost[3];
        const float hpr = (sj == 0) ? Hpre[0]  : (sj == 1) ? Hpre[1]
                        : (sj == 2) ? Hpre[2]  : Hpre[3];
        wsf[(size_t)blk * 64 + g * 16 + si * 4 + sj] = fmaf(hpo, hpr, Mv);
    }
    #undef STAGE_TILE
}

// ---------------- Kernel B: streaming mix  out = W . x ----------------
__global__ __launch_bounds__(256) void lora_mix_kernel(
    const float* __restrict__ x,
    const float* __restrict__ wsf,
    float* __restrict__ out)
{
    const int tok = blockIdx.x;
    const int c4  = threadIdx.x;            // 0..255 column-of-float4

    const float4* __restrict__ x4p = (const float4*)x   + (size_t)tok * NC4;
    float4* __restrict__       out4 = (float4*)out      + (size_t)tok * NC4;
    const float4* __restrict__ w4   = (const float4*)wsf + (size_t)tok * 4;

    // W rows: same address across the wave -> broadcast loads
    const float4 W0 = w4[0];
    const float4 W1 = w4[1];
    const float4 W2 = w4[2];
    const float4 W3 = w4[3];

    const float4 x0 = x4p[0 * 256 + c4];
    const float4 x1 = x4p[1 * 256 + c4];
    const float4 x2 = x4p[2 * 256 + c4];
    const float4 x3 = x4p[3 * 256 + c4];

    // identical FMA chain order to the fused version (bitwise-stable)
    #define MIXROW(WR, DSTIDX)                                                    \
    {                                                                             \
        float4 o;                                                                 \
        o.x = fmaf(WR.x, x0.x, fmaf(WR.y, x1.x, fmaf(WR.z, x2.x, WR.w * x3.x)));  \
        o.y = fmaf(WR.x, x0.y, fmaf(WR.y, x1.y, fmaf(WR.z, x2.y, WR.w * x3.y)));  \
        o.z = fmaf(WR.x, x0.z, fmaf(WR.y, x1.z, fmaf(WR.z, x2.z, WR.w * x3.z)));  \
        o.w = fmaf(WR.x, x0.w, fmaf(WR.y, x1.w, fmaf(WR.z, x2.w, WR.w * x3.w)));  \
        out4[(DSTIDX) * 256 + c4] = o;                                            \
    }
    MIXROW(W0, 0);
    MIXROW(W1, 1);
    MIXROW(W2, 2);
    MIXROW(W3, 3);
    #undef MIXROW
}

extern "C" void kernel_launch(void* const* d_in, const int* in_sizes, int n_in,
                              void* d_out, int out_size, void* d_ws, size_t ws_size,
                              hipStream_t stream) {
    const float* x         = (const float*)d_in[0];
    const float* inw       = (const float*)d_in[1];
    const float* phi_pre   = (const float*)d_in[2];
    const float* phi_post  = (const float*)d_in[3];
    const float* phi_res   = (const float*)d_in[4];
    const float* b_pre     = (const float*)d_in[5];
    const float* b_post    = (const float*)d_in[6];
    const float* b_res     = (const float*)d_in[7];
    const float* alpha_pre = (const float*)d_in[8];
    const float* alpha_post= (const float*)d_in[9];
    const float* alpha_res = (const float*)d_in[10];
    const int*   adapter   = (const int*)d_in[11];
    float* out = (float*)d_out;
    float* wsf = (float*)d_ws;               // 8192 * 16 floats = 512 KB

    dim3 block(256);
    lora_w_kernel<<<dim3(BT / 4), block, 0, stream>>>(
        x, inw, phi_pre, phi_post, phi_res,
        b_pre, b_post, b_res,
        alpha_pre, alpha_post, alpha_res,
        adapter, wsf);
    lora_mix_kernel<<<dim3(BT), block, 0, stream>>>(x, wsf, out);
}